// Round 3
// baseline (215.435 us; speedup 1.0000x reference)
//
#include <hip/hip_runtime.h>

// MultiScaleTrendDirectionLoss — B=32, T=8192, D=64, fp32 in, scalar fp32 out.
// R11: cross-round evidence (R8: 192 scalar loads/wave vs R10: 48 dwordx4
// loads/wave — same bytes, SAME 48µs) shows the limiter tracks LOGICAL BYTES,
// not request count/width/depth: time ~= logical_bytes / 4.2 TB/s across all
// structures. Rate-side levers are exhausted (R9 depth, R10 width both null).
// This round cuts the numerator: CH=64 -> 128 with the same WU=32 warmup
// drops fetch redundancy 1.5x -> 1.25x (201 -> 167 MB logical). Clean
// discriminator: bytes-model predicts ~40µs despite 2048 waves (2 blocks/CU);
// concurrency-model predicts >=50µs. If the latter, R12 attacks rate at full
// occupancy (global_load_lds + counted vmcnt).
// Accuracy: seed boundaries at s=128c are a SUBSET of R10's s=64c points,
// same WU=32 split warmup -> strictly no worse. Chain0 warms 32 steps
// ((0.9)^32=0.034), chains 1/2 warm 16 ((0.7)^16=3e-3, (0.5)^16=2e-5).
// WU=16 for chain0 is UNSAFE (bias ~2.8e-3 vs thr 3.3e-3) — do not shrink.

namespace {
constexpr int BB  = 32;
constexpr int TT  = 8192;
constexpr int DD  = 64;
constexpr int CH  = 128;        // chunk length along T (was 64)
constexpr int WU  = 32;         // warmup prefix (16 a0-only + 16 all-chain)
constexpr int NCH = TT / CH;    // 64 chunks per sequence
constexpr int WPB = 4;          // waves per block (256 threads)
constexpr int BT  = 16;         // rows (T-steps) per batch
// masked.mean(axis=1) /(T-1)=8191; final .mean() /(B*D)=2048
constexpr float INV_NORM = 1.0f / (8191.0f * 2048.0f);
}

__global__ void zero_out_kernel(float* o) { o[0] = 0.0f; }

// 8 x global_load_dwordx4: one 16-row batch (x and y).
__device__ __forceinline__ void gload(const float* __restrict__ pv,
                                      const float* __restrict__ qv, int bt,
                                      float4 (&rx)[4], float4 (&ry)[4]) {
#pragma unroll
  for (int j = 0; j < 4; ++j) {
    rx[j] = *reinterpret_cast<const float4*>(pv + (bt + 4 * j) * DD);
    ry[j] = *reinterpret_cast<const float4*>(qv + (bt + 4 * j) * DD);
  }
}

// 8 x ds_write_b128 into the wave-private tile.
__device__ __forceinline__ void stage(float* __restrict__ lx,
                                      float* __restrict__ ly,
                                      const float4 (&rx)[4], const float4 (&ry)[4]) {
#pragma unroll
  for (int j = 0; j < 4; ++j) {
    *reinterpret_cast<float4*>(lx + 4 * j * DD) = rx[j];
    *reinterpret_cast<float4*>(ly + 4 * j * DD) = ry[j];
  }
}

// warmup, chain0 only (alpha=0.1), from tile
__device__ __forceinline__ void warm16_a0_t(const float* __restrict__ tx,
                                            const float* __restrict__ ty,
                                            float& pe0, float& te0) {
#pragma unroll
  for (int i = 0; i < BT; ++i) {
    float xx = tx[i * DD], yy = ty[i * DD];
    pe0 = fmaf(0.1f, xx - pe0, pe0);
    te0 = fmaf(0.1f, yy - te0, te0);
  }
}

// warmup, all chains, no accumulation, from tile
__device__ __forceinline__ void warm16_all_t(const float* __restrict__ tx,
    const float* __restrict__ ty,
    float& pe0, float& te0, float& pe1, float& te1, float& pe2, float& te2) {
#pragma unroll
  for (int i = 0; i < BT; ++i) {
    float xx = tx[i * DD], yy = ty[i * DD];
    pe0 = fmaf(0.1f, xx - pe0, pe0);  te0 = fmaf(0.1f, yy - te0, te0);
    pe1 = fmaf(0.3f, xx - pe1, pe1);  te1 = fmaf(0.3f, yy - te1, te1);
    pe2 = fmaf(0.5f, xx - pe2, pe2);  te2 = fmaf(0.5f, yy - te2, te2);
  }
}

__device__ __forceinline__ void step1(float xx, float yy, float a, float w,
                                      float& pe, float& te, float& acc) {
  float dx = xx - pe;
  float dy = yy - te;
  pe = fmaf(a, dx, pe);
  te = fmaf(a, dy, te);
  float e   = pe - te;
  float sel = (dx * dy < 0.0f) ? w : 0.0f;  // sign(a*dx)==sign(dx); ==0 cases
  acc = fmaf(sel, e * e, acc);              // are measure-zero on random data
}

// main: all chains, masked accumulate, from tile
__device__ __forceinline__ void acc16_t(const float* __restrict__ tx,
    const float* __restrict__ ty,
    float& pe0, float& te0, float& pe1, float& te1, float& pe2, float& te2,
    float& acc) {
#pragma unroll
  for (int i = 0; i < BT; ++i) {
    float xx = tx[i * DD], yy = ty[i * DD];
    step1(xx, yy, 0.1f, 0.5f, pe0, te0, acc);
    step1(xx, yy, 0.3f, 0.3f, pe1, te1, acc);
    step1(xx, yy, 0.5f, 0.2f, pe2, te2, acc);
  }
}

__global__ void __launch_bounds__(256)
__attribute__((amdgpu_waves_per_eu(4, 4)))
ms_trend_loss_kernel(const float* __restrict__ pred,
                     const float* __restrict__ targ,
                     float* __restrict__ out) {
  const int lane = threadIdx.x & 63;
  const int wave = threadIdx.x >> 6;
  const int unit = blockIdx.x * WPB + wave;   // 0 .. BB*NCH-1 (2048)
  const int b = unit >> 6;                    // / NCH (NCH=64)
  const int c = unit & 63;                    // % NCH
  const int s = c * CH;
  const int start = (c == 0) ? 0 : (s - WU);  // >= 0 (WU < CH)

  const int rsub = lane >> 4;                 // row-in-quad 0..3
  const int csub = (lane & 15) * 4;           // col group 0,4,..,60

  // cooperative-load base: row rsub, cols csub..csub+3
  const float* pv = pred + (b * TT + start) * DD + rsub * DD + csub;
  const float* qv = targ + (b * TT + start) * DD + rsub * DD + csub;

  // wave-private transpose tile: [16 rows][64 cols] per array
  __shared__ float lds_x[WPB][BT * DD];
  __shared__ float lds_y[WPB][BT * DD];
  float* lxw = &lds_x[wave][rsub * DD + csub];  // write base
  float* lyw = &lds_y[wave][rsub * DD + csub];
  const float* txr = &lds_x[wave][lane];        // read base (own column)
  const float* tyr = &lds_y[wave][lane];

  float pe0, pe1, pe2, te0, te1, te2;
  float acc = 0.0f;
  float4 ax[4], ay[4], bx[4], by[4];            // A/B in-flight sets

  if (c == 0) {
    // exact path: 128 accumulated steps, t in [0, 128). First step re-sees
    // row 0: dx=dy=0 -> no-op, matching ema_0 = x_0.  Batches 0..7.
    gload(pv, qv, 0, ax, ay);
    gload(pv, qv, BT, bx, by);
    __builtin_amdgcn_sched_barrier(0);
    stage(lxw, lyw, ax, ay);                    // b0 -> tile
    gload(pv, qv, 2 * BT, ax, ay);
    __builtin_amdgcn_sched_barrier(0);
    pe0 = pe1 = pe2 = txr[0];
    te0 = te1 = te2 = tyr[0];
    acc16_t(txr, tyr, pe0, te0, pe1, te1, pe2, te2, acc);   // b0
    stage(lxw, lyw, bx, by);
    gload(pv, qv, 3 * BT, bx, by);
    __builtin_amdgcn_sched_barrier(0);
    acc16_t(txr, tyr, pe0, te0, pe1, te1, pe2, te2, acc);   // b1
    stage(lxw, lyw, ax, ay);
    gload(pv, qv, 4 * BT, ax, ay);
    __builtin_amdgcn_sched_barrier(0);
    acc16_t(txr, tyr, pe0, te0, pe1, te1, pe2, te2, acc);   // b2
    stage(lxw, lyw, bx, by);
    gload(pv, qv, 5 * BT, bx, by);
    __builtin_amdgcn_sched_barrier(0);
    acc16_t(txr, tyr, pe0, te0, pe1, te1, pe2, te2, acc);   // b3
    stage(lxw, lyw, ax, ay);
    gload(pv, qv, 6 * BT, ax, ay);
    __builtin_amdgcn_sched_barrier(0);
    acc16_t(txr, tyr, pe0, te0, pe1, te1, pe2, te2, acc);   // b4
    stage(lxw, lyw, bx, by);
    gload(pv, qv, 7 * BT, bx, by);
    __builtin_amdgcn_sched_barrier(0);
    acc16_t(txr, tyr, pe0, te0, pe1, te1, pe2, te2, acc);   // b5
    stage(lxw, lyw, ax, ay);
    acc16_t(txr, tyr, pe0, te0, pe1, te1, pe2, te2, acc);   // b6
    stage(lxw, lyw, bx, by);
    acc16_t(txr, tyr, pe0, te0, pe1, te1, pe2, te2, acc);   // b7
  } else {
    // warmup t in [s-32, s-16): chain0 only; [s-16, s): all chains;
    // accumulate t in [s, s+128).  Batches 0..9 (2 warm + 8 acc).
    gload(pv, qv, 0, ax, ay);
    gload(pv, qv, BT, bx, by);
    __builtin_amdgcn_sched_barrier(0);
    stage(lxw, lyw, ax, ay);                    // b0
    gload(pv, qv, 2 * BT, ax, ay);
    __builtin_amdgcn_sched_barrier(0);
    pe0 = txr[0];
    te0 = tyr[0];
    warm16_a0_t(txr, tyr, pe0, te0);            // b0
    stage(lxw, lyw, bx, by);                    // b1
    gload(pv, qv, 3 * BT, bx, by);
    __builtin_amdgcn_sched_barrier(0);
    pe1 = pe2 = txr[0];                         // == x[s-16], as before
    te1 = te2 = tyr[0];
    warm16_all_t(txr, tyr, pe0, te0, pe1, te1, pe2, te2);   // b1
    stage(lxw, lyw, ax, ay);                    // b2
    gload(pv, qv, 4 * BT, ax, ay);
    __builtin_amdgcn_sched_barrier(0);
    acc16_t(txr, tyr, pe0, te0, pe1, te1, pe2, te2, acc);   // b2
    stage(lxw, lyw, bx, by);                    // b3
    gload(pv, qv, 5 * BT, bx, by);
    __builtin_amdgcn_sched_barrier(0);
    acc16_t(txr, tyr, pe0, te0, pe1, te1, pe2, te2, acc);   // b3
    stage(lxw, lyw, ax, ay);                    // b4
    gload(pv, qv, 6 * BT, ax, ay);
    __builtin_amdgcn_sched_barrier(0);
    acc16_t(txr, tyr, pe0, te0, pe1, te1, pe2, te2, acc);   // b4
    stage(lxw, lyw, bx, by);                    // b5
    gload(pv, qv, 7 * BT, bx, by);
    __builtin_amdgcn_sched_barrier(0);
    acc16_t(txr, tyr, pe0, te0, pe1, te1, pe2, te2, acc);   // b5
    stage(lxw, lyw, ax, ay);                    // b6
    gload(pv, qv, 8 * BT, ax, ay);
    __builtin_amdgcn_sched_barrier(0);
    acc16_t(txr, tyr, pe0, te0, pe1, te1, pe2, te2, acc);   // b6
    stage(lxw, lyw, bx, by);                    // b7
    gload(pv, qv, 9 * BT, bx, by);
    __builtin_amdgcn_sched_barrier(0);
    acc16_t(txr, tyr, pe0, te0, pe1, te1, pe2, te2, acc);   // b7
    stage(lxw, lyw, ax, ay);                    // b8
    acc16_t(txr, tyr, pe0, te0, pe1, te1, pe2, te2, acc);   // b8
    stage(lxw, lyw, bx, by);                    // b9
    acc16_t(txr, tyr, pe0, te0, pe1, te1, pe2, te2, acc);   // b9
  }

  // wave-64 shuffle reduce -> per-block LDS reduce -> 1 atomic per block
#pragma unroll
  for (int off = 32; off > 0; off >>= 1) acc += __shfl_down(acc, off);
  __shared__ float sred[WPB];
  if (lane == 0) sred[wave] = acc;
  __syncthreads();
  if (threadIdx.x == 0) {
    float t = sred[0] + sred[1] + sred[2] + sred[3];
    atomicAdd(out, t * INV_NORM);
  }
}

extern "C" void kernel_launch(void* const* d_in, const int* in_sizes, int n_in,
                              void* d_out, int out_size, void* d_ws, size_t ws_size,
                              hipStream_t stream) {
  (void)in_sizes; (void)n_in; (void)out_size; (void)d_ws; (void)ws_size;
  const float* pred = (const float*)d_in[0];
  const float* targ = (const float*)d_in[1];
  float* out = (float*)d_out;

  zero_out_kernel<<<1, 1, 0, stream>>>(out);
  ms_trend_loss_kernel<<<BB * NCH / WPB, 256, 0, stream>>>(pred, targ, out);
}

// Round 4
// 157.284 us; speedup vs baseline: 1.3697x; 1.3697x over previous
//
#include <hip/hip_runtime.h>

// MultiScaleTrendDirectionLoss — B=32, T=8192, D=64, fp32 in, scalar fp32 out.
// R12: R11 post-mortem — WRITE_SIZE 161 MB = scratch spill of the float4 sets
// (3rd straight round regalloc sabotaged a VGPR-resident pipeline; 10-batch
// straight-line body pushed it over). Also, clean-round fit (R4-R7 268MB@53µs
// vs R8/R10 201MB@48µs) shows marginal byte-rate is fast with a large fixed
// component: waves burst loads then sit with ZERO memory in flight (avg 0.4
// loads/wave outstanding) because compiler-scheduled waits drain everything.
// Fix: take VGPRs out of the datapath — __builtin_amdgcn_global_load_lds
// (width 16) into double-buffered wave-private LDS, with EXPLICIT counted
// s_waitcnt vmcnt(4) (never 0 in the loop, m218 discipline). No VGPR dests ->
// nothing to spill/collapse. 16 waves/CU x 4 KB outstanding = 64 KB/CU in
// flight >> HBM-rate requirement.
// Math: bit-identical t-order/seeds to R8 (CH=64, WU=32) -> absmax 0.0.
// Accuracy contract: chain0 warms 32 steps ((0.9)^32=0.034), chains 1/2 warm
// 16 ((0.7)^16=3e-3, (0.5)^16=2e-5). WU=16 for chain0 is UNSAFE — don't shrink.

namespace {
constexpr int BB  = 32;
constexpr int TT  = 8192;
constexpr int DD  = 64;
constexpr int CH  = 64;         // chunk length along T
constexpr int WU  = 32;         // warmup prefix (16 a0-only + 16 all-chain)
constexpr int NCH = TT / CH;    // 128 chunks per sequence
constexpr int WPB = 4;          // waves per block (256 threads)
constexpr int BT  = 8;          // rows per load batch (2 KB per array)
// masked.mean(axis=1) /(T-1)=8191; final .mean() /(B*D)=2048
constexpr float INV_NORM = 1.0f / (8191.0f * 2048.0f);
}

typedef const __attribute__((address_space(1))) void* gas_ptr;
typedef __attribute__((address_space(3))) void* las_ptr;

__global__ void zero_out_kernel(float* o) { o[0] = 0.0f; }

// Counted waits. "memory" clobber orders the surrounding LDS reads/DMA issues;
// sched_barrier(0) stops the scheduler hoisting anything past the wait (#18).
#define WAIT_V4() do { asm volatile("s_waitcnt vmcnt(4)" ::: "memory"); \
                       __builtin_amdgcn_sched_barrier(0); } while (0)
#define WAIT_V0() do { asm volatile("s_waitcnt vmcnt(0)" ::: "memory"); \
                       __builtin_amdgcn_sched_barrier(0); } while (0)
#define WAIT_LG() do { asm volatile("s_waitcnt lgkmcnt(0)" ::: "memory"); \
                       __builtin_amdgcn_sched_barrier(0); } while (0)

// One batch = 8 rows x 64 cols x {x,y} = 4 x global_load_lds_dwordx4 (1KB per
// instr). gx/gy are PER-LANE global srcs (base + lane*4 floats); lx/ly are
// WAVE-UNIFORM LDS dsts (HW writes base + lane*16 — linear, matches row-major
// tile since each 1KB region is 4 contiguous rows).
__device__ __forceinline__ void issue_batch(const float* gx, const float* gy,
                                            float* lx, float* ly) {
#pragma unroll
  for (int r = 0; r < 2; ++r) {
    __builtin_amdgcn_global_load_lds((gas_ptr)(gx + r * 4 * DD),
                                     (las_ptr)(lx + r * 4 * DD), 16, 0, 0);
    __builtin_amdgcn_global_load_lds((gas_ptr)(gy + r * 4 * DD),
                                     (las_ptr)(ly + r * 4 * DD), 16, 0, 0);
  }
}

// warmup, chain0 only (alpha=0.1), from tile (stride DD, own column)
__device__ __forceinline__ void warm8_a0(const float* tx, const float* ty,
                                         float& pe0, float& te0) {
#pragma unroll
  for (int i = 0; i < BT; ++i) {
    float xx = tx[i * DD], yy = ty[i * DD];
    pe0 = fmaf(0.1f, xx - pe0, pe0);
    te0 = fmaf(0.1f, yy - te0, te0);
  }
}

// warmup, all chains, no accumulation
__device__ __forceinline__ void warm8_all(const float* tx, const float* ty,
    float& pe0, float& te0, float& pe1, float& te1, float& pe2, float& te2) {
#pragma unroll
  for (int i = 0; i < BT; ++i) {
    float xx = tx[i * DD], yy = ty[i * DD];
    pe0 = fmaf(0.1f, xx - pe0, pe0);  te0 = fmaf(0.1f, yy - te0, te0);
    pe1 = fmaf(0.3f, xx - pe1, pe1);  te1 = fmaf(0.3f, yy - te1, te1);
    pe2 = fmaf(0.5f, xx - pe2, pe2);  te2 = fmaf(0.5f, yy - te2, te2);
  }
}

__device__ __forceinline__ void step1(float xx, float yy, float a, float w,
                                      float& pe, float& te, float& acc) {
  float dx = xx - pe;
  float dy = yy - te;
  pe = fmaf(a, dx, pe);
  te = fmaf(a, dy, te);
  float e   = pe - te;
  float sel = (dx * dy < 0.0f) ? w : 0.0f;  // sign(a*dx)==sign(dx); ==0 cases
  acc = fmaf(sel, e * e, acc);              // are measure-zero on random data
}

// main: all chains, masked accumulate
__device__ __forceinline__ void acc8(const float* tx, const float* ty,
    float& pe0, float& te0, float& pe1, float& te1, float& pe2, float& te2,
    float& acc) {
#pragma unroll
  for (int i = 0; i < BT; ++i) {
    float xx = tx[i * DD], yy = ty[i * DD];
    step1(xx, yy, 0.1f, 0.5f, pe0, te0, acc);
    step1(xx, yy, 0.3f, 0.3f, pe1, te1, acc);
    step1(xx, yy, 0.5f, 0.2f, pe2, te2, acc);
  }
}

__global__ void __launch_bounds__(256)
ms_trend_loss_kernel(const float* __restrict__ pred,
                     const float* __restrict__ targ,
                     float* __restrict__ out) {
  const int lane = threadIdx.x & 63;
  const int wave = threadIdx.x >> 6;
  const int unit = blockIdx.x * WPB + wave;   // 0 .. BB*NCH-1 (4096)
  const int b = unit >> 7;                    // / NCH (NCH=128)
  const int c = unit & 127;                   // % NCH
  const int s = c * CH;
  const int start = (c == 0) ? 0 : (s - WU);  // >= 0 (WU < CH)

  const float* gx = pred + (b * TT + start) * DD + lane * 4;  // per-lane src
  const float* gy = targ + (b * TT + start) * DD + lane * 4;

  // wave-private double-buffered tile: [wave][buf][x/y][8 rows * 64 cols]
  __shared__ float tile[WPB][2][2][BT * DD];
#define LX(k) (&tile[wave][(k) & 1][0][0])
#define LY(k) (&tile[wave][(k) & 1][1][0])
#define TX(k) (&tile[wave][(k) & 1][0][lane])
#define TY(k) (&tile[wave][(k) & 1][1][lane])

  float pe0, pe1, pe2, te0, te1, te2;
  float acc = 0.0f;

  // prologue: 2 batches (8 loads) in flight
  issue_batch(gx, gy, LX(0), LY(0));
  issue_batch(gx + BT * DD, gy + BT * DD, LX(1), LY(1));

  if (c == 0) {
    // exact path: 64 accumulated steps (batches 0..7). First step re-sees
    // row 0: dx=dy=0 -> no-op, matching ema_0 = x_0.
    WAIT_V4();
    pe0 = pe1 = pe2 = TX(0)[0];
    te0 = te1 = te2 = TY(0)[0];
    acc8(TX(0), TY(0), pe0, te0, pe1, te1, pe2, te2, acc);
    WAIT_LG();
    issue_batch(gx + 2 * BT * DD, gy + 2 * BT * DD, LX(0), LY(0));
    for (int k = 1; k < 6; ++k) {           // issues batches 3..7
      WAIT_V4();
      acc8(TX(k), TY(k), pe0, te0, pe1, te1, pe2, te2, acc);
      WAIT_LG();
      issue_batch(gx + (k + 2) * BT * DD, gy + (k + 2) * BT * DD, LX(k), LY(k));
    }
    WAIT_V4();
    acc8(TX(6), TY(6), pe0, te0, pe1, te1, pe2, te2, acc);
    WAIT_V0();
    acc8(TX(7), TY(7), pe0, te0, pe1, te1, pe2, te2, acc);
  } else {
    // warmup t in [s-32, s-16): chain0 only (batches 0,1);
    // [s-16, s): all chains (batches 2,3); accumulate batches 4..11.
    WAIT_V4();
    pe0 = TX(0)[0];
    te0 = TY(0)[0];
    warm8_a0(TX(0), TY(0), pe0, te0);
    WAIT_LG();
    issue_batch(gx + 2 * BT * DD, gy + 2 * BT * DD, LX(0), LY(0));
    WAIT_V4();
    warm8_a0(TX(1), TY(1), pe0, te0);
    WAIT_LG();
    issue_batch(gx + 3 * BT * DD, gy + 3 * BT * DD, LX(1), LY(1));
    WAIT_V4();
    pe1 = pe2 = TX(2)[0];                   // == x[s-16], as in R8
    te1 = te2 = TY(2)[0];
    warm8_all(TX(2), TY(2), pe0, te0, pe1, te1, pe2, te2);
    WAIT_LG();
    issue_batch(gx + 4 * BT * DD, gy + 4 * BT * DD, LX(2), LY(2));
    WAIT_V4();
    warm8_all(TX(3), TY(3), pe0, te0, pe1, te1, pe2, te2);
    WAIT_LG();
    issue_batch(gx + 5 * BT * DD, gy + 5 * BT * DD, LX(3), LY(3));
    for (int k = 4; k < 10; ++k) {          // issues batches 6..11
      WAIT_V4();
      acc8(TX(k), TY(k), pe0, te0, pe1, te1, pe2, te2, acc);
      WAIT_LG();
      issue_batch(gx + (k + 2) * BT * DD, gy + (k + 2) * BT * DD, LX(k), LY(k));
    }
    WAIT_V4();
    acc8(TX(10), TY(10), pe0, te0, pe1, te1, pe2, te2, acc);
    WAIT_V0();
    acc8(TX(11), TY(11), pe0, te0, pe1, te1, pe2, te2, acc);
  }

  // wave-64 shuffle reduce -> per-block LDS reduce -> 1 atomic per block
#pragma unroll
  for (int off = 32; off > 0; off >>= 1) acc += __shfl_down(acc, off);
  __shared__ float sred[WPB];
  if (lane == 0) sred[wave] = acc;
  __syncthreads();
  if (threadIdx.x == 0) {
    float t = sred[0] + sred[1] + sred[2] + sred[3];
    atomicAdd(out, t * INV_NORM);
  }
}

extern "C" void kernel_launch(void* const* d_in, const int* in_sizes, int n_in,
                              void* d_out, int out_size, void* d_ws, size_t ws_size,
                              hipStream_t stream) {
  (void)in_sizes; (void)n_in; (void)out_size; (void)d_ws; (void)ws_size;
  const float* pred = (const float*)d_in[0];
  const float* targ = (const float*)d_in[1];
  float* out = (float*)d_out;

  zero_out_kernel<<<1, 1, 0, stream>>>(out);
  ms_trend_loss_kernel<<<BB * NCH / WPB, 256, 0, stream>>>(pred, targ, out);
}

// Round 6
// 153.290 us; speedup vs baseline: 1.4054x; 1.0261x over previous
//
#include <hip/hip_runtime.h>

// MultiScaleTrendDirectionLoss — B=32, T=8192, D=64, fp32 in, scalar fp32 out.
// R13b: identical to R13 (previous bench died at container level, no data).
// R12 exonerated codegen (VGPR 52, no spill, counted vmcnt working) yet still
// 53µs @ 1.9 TB/s. Cross-round law: time = FETCH / ~2.0 TB/s for every
// structure (R11 incl. spills: 316MB/128µs = 2.46 TB/s fits). Queueing math
// (16-32 MB outstanding vs 833 B/cy drain = observed 10k cy/batch wall) says
// the HBM-side SERVICE RATE for this pattern is the wall, not concurrency.
// vs the 6.3 TB/s copy reference the difference is stream shape: 4096 private
// 24KB streams in 2KB visits. R13 tests that axis: 1024 streams x 72KB
// (CH=256, redundancy 1.125), 8KB contiguous per visit (BT=16), triple-buffer
// LDS ring (24KB/wave), vmcnt(8) keeps 16KB/wave in flight continuously.
// WPB=2 (128-thr blocks, 48KB LDS, 3 blocks/CU capacity for 512 blocks).
// If ~50µs again: stream shape+depth+width+count+codegen all falsified at
// 2 TB/s -> system-level cap -> declare roofline.
// Accuracy: seeds {256c} subset of R8's verified {64c}; same WU=32 split
// warmup (chain0 32 steps (0.9)^32=0.034; chains 1/2 16 steps (0.7)^16=3e-3,
// (0.5)^16=2e-5); same step order -> error <= R8's measured absmax 0.0.
// WU=16 for chain0 is UNSAFE (bias ~2.8e-3 vs thr 3.3e-3) — do not shrink.

namespace {
constexpr int BB  = 32;
constexpr int TT  = 8192;
constexpr int DD  = 64;
constexpr int CH  = 256;        // chunk length along T
constexpr int WU  = 32;         // warmup prefix (16 a0-only + 16 all-chain)
constexpr int NCH = TT / CH;    // 32 chunks per sequence
constexpr int WPB = 2;          // waves per block (128 threads)
constexpr int BT  = 16;         // rows per batch (4 KB per array per batch)
constexpr int NBUF = 3;         // LDS ring depth (2 batches always in flight)
// masked.mean(axis=1) /(T-1)=8191; final .mean() /(B*D)=2048
constexpr float INV_NORM = 1.0f / (8191.0f * 2048.0f);
}

typedef const __attribute__((address_space(1))) void* gas_ptr;
typedef __attribute__((address_space(3))) void* las_ptr;

__global__ void zero_out_kernel(float* o) { o[0] = 0.0f; }

#define SBAR() __builtin_amdgcn_sched_barrier(0)
// counted waits: never drain to 0 in the loop (m218 discipline)
#define WAIT_V8() do { asm volatile("s_waitcnt vmcnt(8)" ::: "memory"); SBAR(); } while (0)
#define WAIT_V0() do { asm volatile("s_waitcnt vmcnt(0)" ::: "memory"); SBAR(); } while (0)

// One batch = 16 rows x 64 cols x {x,y} = 8 x global_load_lds_dwordx4
// (1 KB per instr; 4 KB contiguous per array). gx/gy are PER-LANE global srcs
// (base + lane*16B); lx/ly are WAVE-UNIFORM LDS dsts (HW writes base +
// lane*16B — linear, matches the row-major tile: each instr = 4 rows).
__device__ __forceinline__ void issue_batch(const float* gx, const float* gy,
                                            float* lx, float* ly) {
#pragma unroll
  for (int r = 0; r < 4; ++r) {
    __builtin_amdgcn_global_load_lds((gas_ptr)(gx + r * 4 * DD),
                                     (las_ptr)(lx + r * 4 * DD), 16, 0, 0);
    __builtin_amdgcn_global_load_lds((gas_ptr)(gy + r * 4 * DD),
                                     (las_ptr)(ly + r * 4 * DD), 16, 0, 0);
  }
  SBAR();
}

// warmup, chain0 only (alpha=0.1), from tile (stride DD, own column)
__device__ __forceinline__ void warm16_a0_t(const float* tx, const float* ty,
                                            float& pe0, float& te0) {
#pragma unroll
  for (int i = 0; i < BT; ++i) {
    float xx = tx[i * DD], yy = ty[i * DD];
    pe0 = fmaf(0.1f, xx - pe0, pe0);
    te0 = fmaf(0.1f, yy - te0, te0);
  }
}

// warmup, all chains, no accumulation
__device__ __forceinline__ void warm16_all_t(const float* tx, const float* ty,
    float& pe0, float& te0, float& pe1, float& te1, float& pe2, float& te2) {
#pragma unroll
  for (int i = 0; i < BT; ++i) {
    float xx = tx[i * DD], yy = ty[i * DD];
    pe0 = fmaf(0.1f, xx - pe0, pe0);  te0 = fmaf(0.1f, yy - te0, te0);
    pe1 = fmaf(0.3f, xx - pe1, pe1);  te1 = fmaf(0.3f, yy - te1, te1);
    pe2 = fmaf(0.5f, xx - pe2, pe2);  te2 = fmaf(0.5f, yy - te2, te2);
  }
}

__device__ __forceinline__ void step1(float xx, float yy, float a, float w,
                                      float& pe, float& te, float& acc) {
  float dx = xx - pe;
  float dy = yy - te;
  pe = fmaf(a, dx, pe);
  te = fmaf(a, dy, te);
  float e   = pe - te;
  float sel = (dx * dy < 0.0f) ? w : 0.0f;  // sign(a*dx)==sign(dx); ==0 cases
  acc = fmaf(sel, e * e, acc);              // are measure-zero on random data
}

// main: all chains, masked accumulate
__device__ __forceinline__ void acc16_t(const float* tx, const float* ty,
    float& pe0, float& te0, float& pe1, float& te1, float& pe2, float& te2,
    float& acc) {
#pragma unroll
  for (int i = 0; i < BT; ++i) {
    float xx = tx[i * DD], yy = ty[i * DD];
    step1(xx, yy, 0.1f, 0.5f, pe0, te0, acc);
    step1(xx, yy, 0.3f, 0.3f, pe1, te1, acc);
    step1(xx, yy, 0.5f, 0.2f, pe2, te2, acc);
  }
}

__global__ void __launch_bounds__(128)
ms_trend_loss_kernel(const float* __restrict__ pred,
                     const float* __restrict__ targ,
                     float* __restrict__ out) {
  const int lane = threadIdx.x & 63;
  const int wave = threadIdx.x >> 6;
  const int unit = blockIdx.x * WPB + wave;   // 0 .. BB*NCH-1 (1024)
  const int b = unit >> 5;                    // / NCH (NCH=32)
  const int c = unit & 31;                    // % NCH
  const int start = (c == 0) ? 0 : (c * CH - WU);
  const int nb = (c == 0) ? (CH / BT) : ((CH + WU) / BT);  // 16 or 18

  const float* gx = pred + (b * TT + start) * DD + lane * 4;  // per-lane src
  const float* gy = targ + (b * TT + start) * DD + lane * 4;

  // per-wave triple-buffered tile: [wave][buf][x/y][16 rows * 64 cols]
  __shared__ float tile[WPB][NBUF][2][BT * DD];   // 48 KB

  float pe0 = 0.f, pe1 = 0.f, pe2 = 0.f, te0 = 0.f, te1 = 0.f, te2 = 0.f;
  float acc = 0.0f;

  // prologue: 2 batches (16 DMA instrs, 16 KB) in flight
  issue_batch(gx,           gy,           &tile[wave][0][0][0], &tile[wave][0][1][0]);
  issue_batch(gx + BT * DD, gy + BT * DD, &tile[wave][1][0][0], &tile[wave][1][1][0]);

  int rb = 0;                                 // ring index of compute buffer
  for (int k = 0; k < nb; ++k) {
    // steady state: 16 outstanding at entry; V8 completes batch k, leaves
    // batch k+1's 8 in flight. Only the last batch drains to 0.
    if (k < nb - 1) { WAIT_V8(); } else { WAIT_V0(); }
    const float* tx = &tile[wave][rb][0][lane];
    const float* ty = &tile[wave][rb][1][lane];
    if (c == 0) {
      // exact path: first step re-sees row 0: dx=dy=0 -> no-op == ema_0=x_0.
      if (k == 0) { pe0 = pe1 = pe2 = tx[0]; te0 = te1 = te2 = ty[0]; }
      acc16_t(tx, ty, pe0, te0, pe1, te1, pe2, te2, acc);
    } else {
      if (k == 0) {            // t in [s-32, s-16): chain0 only
        pe0 = tx[0]; te0 = ty[0];
        warm16_a0_t(tx, ty, pe0, te0);
      } else if (k == 1) {     // t in [s-16, s): all chains (seed == x[s-16])
        pe1 = pe2 = tx[0]; te1 = te2 = ty[0];
        warm16_all_t(tx, ty, pe0, te0, pe1, te1, pe2, te2);
      } else {                 // t in [s, s+256): accumulate
        acc16_t(tx, ty, pe0, te0, pe1, te1, pe2, te2, acc);
      }
    }
    SBAR();
    if (k + 2 < nb) {
      // target buffer (k+2)%3 was last read at batch k-1 — reads retired.
      int ib = rb + 2; if (ib >= NBUF) ib -= NBUF;
      issue_batch(gx + (k + 2) * BT * DD, gy + (k + 2) * BT * DD,
                  &tile[wave][ib][0][0], &tile[wave][ib][1][0]);
    }
    rb = (rb + 1 == NBUF) ? 0 : rb + 1;
  }

  // wave-64 shuffle reduce -> per-block LDS reduce -> 1 atomic per block
#pragma unroll
  for (int off = 32; off > 0; off >>= 1) acc += __shfl_down(acc, off);
  __shared__ float sred[WPB];
  if (lane == 0) sred[wave] = acc;
  __syncthreads();
  if (threadIdx.x == 0) {
    float t = sred[0] + sred[1];
    atomicAdd(out, t * INV_NORM);
  }
}

extern "C" void kernel_launch(void* const* d_in, const int* in_sizes, int n_in,
                              void* d_out, int out_size, void* d_ws, size_t ws_size,
                              hipStream_t stream) {
  (void)in_sizes; (void)n_in; (void)out_size; (void)d_ws; (void)ws_size;
  const float* pred = (const float*)d_in[0];
  const float* targ = (const float*)d_in[1];
  float* out = (float*)d_out;

  zero_out_kernel<<<1, 1, 0, stream>>>(out);
  ms_trend_loss_kernel<<<BB * NCH / WPB, WPB * 64, 0, stream>>>(pred, targ, out);
}

// Round 7
// 148.816 us; speedup vs baseline: 1.4477x; 1.0301x over previous
//
#include <hip/hip_runtime.h>

// MultiScaleTrendDirectionLoss — B=32, T=8192, D=64, fp32 in, scalar fp32 out.
// R14 = R8 (best: 146.25µs, VGPR 48) + __builtin_nontemporal_load.
// Why: R13 proved L3-warm dispatches (hbm_bytes~16KB) take the SAME 54µs as
// HBM-cold (98MB) ones -> the wall is the CU<->L2 request path, not HBM.
// Cross-round invariant: logical bytes/CU/cy = 6.5 (R8/R10/R12, ~16 waves/CU)
// regardless of request width (2-line vs 8-line instrs) or pipeline depth.
// Little's law: 6.5 B/cy x ~200cy L2 latency ~= 10 x 128B lines in flight per
// CU — a per-CU L1 miss-tracking cap fits ALL observations. Streaming data
// has zero reuse, so nt (L1-bypass) loads are semantically free and test
// whether the cap is L1-allocation-side. 4-line delta from proven kernel.
// Accuracy: identical math/order to R8 (absmax 0.0). CH=64, WU=32 split
// warmup: chain0 32 steps ((0.9)^32=0.034), chains 1/2 16 ((0.7)^16=3e-3,
// (0.5)^16=2e-5). WU=16 for chain0 is UNSAFE (bias 2.8e-3 vs thr 3.3e-3).

namespace {
constexpr int BB  = 32;
constexpr int TT  = 8192;
constexpr int DD  = 64;
constexpr int CH  = 64;         // chunk length along T
constexpr int WU  = 32;         // warmup prefix (16 a0-only + 16 all-chain)
constexpr int NCH = TT / CH;    // 128 chunks per sequence
constexpr int WPB = 4;          // waves per block (256 threads)
constexpr int BT  = 16;         // steps per load batch
// masked.mean(axis=1) /(T-1)=8191; final .mean() /(B*D)=2048
constexpr float INV_NORM = 1.0f / (8191.0f * 2048.0f);
}

__global__ void zero_out_kernel(float* o) { o[0] = 0.0f; }

__device__ __forceinline__ void load16(const float* __restrict__ p,
                                       const float* __restrict__ q, int bt,
                                       float (&xs)[BT], float (&ys)[BT]) {
#pragma unroll
  for (int i = 0; i < BT; ++i) {
    xs[i] = __builtin_nontemporal_load(p + (bt + i) * DD);
    ys[i] = __builtin_nontemporal_load(q + (bt + i) * DD);
  }
}

// warmup, chain0 only (alpha=0.1): 4 VALU/step
__device__ __forceinline__ void warm16_a0(const float (&xs)[BT], const float (&ys)[BT],
                                          float& pe0, float& te0) {
#pragma unroll
  for (int i = 0; i < BT; ++i) {
    pe0 = fmaf(0.1f, xs[i] - pe0, pe0);
    te0 = fmaf(0.1f, ys[i] - te0, te0);
  }
}

// warmup, all chains, no accumulation: 12 VALU/step
__device__ __forceinline__ void warm16_all(const float (&xs)[BT], const float (&ys)[BT],
    float& pe0, float& te0, float& pe1, float& te1, float& pe2, float& te2) {
#pragma unroll
  for (int i = 0; i < BT; ++i) {
    pe0 = fmaf(0.1f, xs[i] - pe0, pe0);  te0 = fmaf(0.1f, ys[i] - te0, te0);
    pe1 = fmaf(0.3f, xs[i] - pe1, pe1);  te1 = fmaf(0.3f, ys[i] - te1, te1);
    pe2 = fmaf(0.5f, xs[i] - pe2, pe2);  te2 = fmaf(0.5f, ys[i] - te2, te2);
  }
}

__device__ __forceinline__ void step1(float xx, float yy, float a, float w,
                                      float& pe, float& te, float& acc) {
  float dx = xx - pe;
  float dy = yy - te;
  pe = fmaf(a, dx, pe);
  te = fmaf(a, dy, te);
  float e   = pe - te;
  float sel = (dx * dy < 0.0f) ? w : 0.0f;  // sign(a*dx)==sign(dx); ==0 cases
  acc = fmaf(sel, e * e, acc);              // are measure-zero on random data
}

// main: all chains, masked accumulate
__device__ __forceinline__ void acc16_all(const float (&xs)[BT], const float (&ys)[BT],
    float& pe0, float& te0, float& pe1, float& te1, float& pe2, float& te2,
    float& acc) {
#pragma unroll
  for (int i = 0; i < BT; ++i) {
    step1(xs[i], ys[i], 0.1f, 0.5f, pe0, te0, acc);
    step1(xs[i], ys[i], 0.3f, 0.3f, pe1, te1, acc);
    step1(xs[i], ys[i], 0.5f, 0.2f, pe2, te2, acc);
  }
}

__global__ __launch_bounds__(256, 4) void ms_trend_loss_kernel(
    const float* __restrict__ pred, const float* __restrict__ targ,
    float* __restrict__ out) {
  const int lane = threadIdx.x & 63;
  const int wave = threadIdx.x >> 6;
  const int unit = blockIdx.x * WPB + wave;   // 0 .. BB*NCH-1
  const int b = unit >> 7;                    // / NCH (NCH=128)
  const int c = unit & 127;                   // % NCH
  const int s = c * CH;
  const int start = (c == 0) ? 0 : (s - WU);  // >= 0 (WU < CH)

  const float* p = pred + (b * TT + start) * DD + lane;
  const float* q = targ + (b * TT + start) * DD + lane;

  float pe0, pe1, pe2, te0, te1, te2;
  float acc = 0.0f;
  // Two buffer sets, alternated in straight-line code: while set X computes,
  // set Y's loads are in flight.
  float xa[BT], ya[BT], xb[BT], yb[BT];

  if (c == 0) {
    // exact path: 64 accumulated steps, t in [0, 64). First step re-sees
    // xa[0]: dx=dy=0 -> no-op, matching ema_0 = x_0.
    load16(p, q, 0, xa, ya);
    load16(p, q, BT, xb, yb);
    pe0 = pe1 = pe2 = xa[0];
    te0 = te1 = te2 = ya[0];
    acc16_all(xa, ya, pe0, te0, pe1, te1, pe2, te2, acc);
    load16(p, q, 2 * BT, xa, ya);
    acc16_all(xb, yb, pe0, te0, pe1, te1, pe2, te2, acc);
    load16(p, q, 3 * BT, xb, yb);
    acc16_all(xa, ya, pe0, te0, pe1, te1, pe2, te2, acc);
    acc16_all(xb, yb, pe0, te0, pe1, te1, pe2, te2, acc);
  } else {
    // warmup t in [s-32, s-16): chain0 only; [s-16, s): all chains;
    // accumulate t in [s, s+64).
    load16(p, q, 0, xa, ya);
    load16(p, q, BT, xb, yb);
    pe0 = xa[0];
    te0 = ya[0];
    warm16_a0(xa, ya, pe0, te0);
    load16(p, q, 2 * BT, xa, ya);
    pe1 = pe2 = xb[0];
    te1 = te2 = yb[0];
    warm16_all(xb, yb, pe0, te0, pe1, te1, pe2, te2);
    load16(p, q, 3 * BT, xb, yb);
    acc16_all(xa, ya, pe0, te0, pe1, te1, pe2, te2, acc);
    load16(p, q, 4 * BT, xa, ya);
    acc16_all(xb, yb, pe0, te0, pe1, te1, pe2, te2, acc);
    load16(p, q, 5 * BT, xb, yb);
    acc16_all(xa, ya, pe0, te0, pe1, te1, pe2, te2, acc);
    acc16_all(xb, yb, pe0, te0, pe1, te1, pe2, te2, acc);
  }

  // wave-64 shuffle reduce -> per-block LDS reduce -> 1 atomic per block
#pragma unroll
  for (int off = 32; off > 0; off >>= 1) acc += __shfl_down(acc, off);
  __shared__ float sred[WPB];
  if (lane == 0) sred[wave] = acc;
  __syncthreads();
  if (threadIdx.x == 0) {
    float t = sred[0] + sred[1] + sred[2] + sred[3];
    atomicAdd(out, t * INV_NORM);
  }
}

extern "C" void kernel_launch(void* const* d_in, const int* in_sizes, int n_in,
                              void* d_out, int out_size, void* d_ws, size_t ws_size,
                              hipStream_t stream) {
  (void)in_sizes; (void)n_in; (void)out_size; (void)d_ws; (void)ws_size;
  const float* pred = (const float*)d_in[0];
  const float* targ = (const float*)d_in[1];
  float* out = (float*)d_out;

  zero_out_kernel<<<1, 1, 0, stream>>>(out);
  ms_trend_loss_kernel<<<BB * NCH / WPB, 256, 0, stream>>>(pred, targ, out);
}

// Round 8
// 143.214 us; speedup vs baseline: 1.5043x; 1.0391x over previous
//
#include <hip/hip_runtime.h>

// MultiScaleTrendDirectionLoss — B=32, T=8192, D=64, fp32 in, scalar fp32 out.
// R15 = R14 (nt loads, CH=64, dispatch <40µs) + CH=128 (redundancy 1.5->1.25,
// logical 201->167 MB).
// Evidence base: R14's kernel VANISHED from the top-5 (slowest dispatches are
// now 40.4µs harness fills) -> dispatch <40µs, logical rate >=5 TB/s = ~80%
// of ceiling. NT/L1-bypass was the wall (per-CU L1 miss-tracking cap); rate
// is now near-roofline, so the remaining lever is the byte NUMERATOR.
// R11's CH=128 failure is defused: its spill came from float4 sets +
// sched_barriers (R14's scalar two-set shape compiles to VGPR 48, no spill);
// pipeline collapse is harmless in the NT regime; CH=128 math already passed
// absmax 0.0 on HW (R11). Occupancy halves (2048 waves) — acceptable: 8 MB
// in flight still covers the pipe at NT service rate.
// Falsifier: WRITE_SIZE jump (spill) or bench >=180 -> revert to R14, declare
// roofline at logical-bytes limit.
// Accuracy contract: WU=32 split warmup. Chain0 warms 32 steps
// ((0.9)^32=0.034), chains 1/2 warm 16 ((0.7)^16=3e-3, (0.5)^16=2e-5).
// WU=16 for chain0 is UNSAFE (bias ~2.8e-3 vs thr 3.3e-3) — do not shrink.

namespace {
constexpr int BB  = 32;
constexpr int TT  = 8192;
constexpr int DD  = 64;
constexpr int CH  = 128;        // chunk length along T (R14: 64)
constexpr int WU  = 32;         // warmup prefix (16 a0-only + 16 all-chain)
constexpr int NCH = TT / CH;    // 64 chunks per sequence
constexpr int WPB = 4;          // waves per block (256 threads)
constexpr int BT  = 16;         // steps per load batch
// masked.mean(axis=1) /(T-1)=8191; final .mean() /(B*D)=2048
constexpr float INV_NORM = 1.0f / (8191.0f * 2048.0f);
}

__global__ void zero_out_kernel(float* o) { o[0] = 0.0f; }

__device__ __forceinline__ void load16(const float* __restrict__ p,
                                       const float* __restrict__ q, int bt,
                                       float (&xs)[BT], float (&ys)[BT]) {
#pragma unroll
  for (int i = 0; i < BT; ++i) {
    xs[i] = __builtin_nontemporal_load(p + (bt + i) * DD);
    ys[i] = __builtin_nontemporal_load(q + (bt + i) * DD);
  }
}

// warmup, chain0 only (alpha=0.1): 4 VALU/step
__device__ __forceinline__ void warm16_a0(const float (&xs)[BT], const float (&ys)[BT],
                                          float& pe0, float& te0) {
#pragma unroll
  for (int i = 0; i < BT; ++i) {
    pe0 = fmaf(0.1f, xs[i] - pe0, pe0);
    te0 = fmaf(0.1f, ys[i] - te0, te0);
  }
}

// warmup, all chains, no accumulation: 12 VALU/step
__device__ __forceinline__ void warm16_all(const float (&xs)[BT], const float (&ys)[BT],
    float& pe0, float& te0, float& pe1, float& te1, float& pe2, float& te2) {
#pragma unroll
  for (int i = 0; i < BT; ++i) {
    pe0 = fmaf(0.1f, xs[i] - pe0, pe0);  te0 = fmaf(0.1f, ys[i] - te0, te0);
    pe1 = fmaf(0.3f, xs[i] - pe1, pe1);  te1 = fmaf(0.3f, ys[i] - te1, te1);
    pe2 = fmaf(0.5f, xs[i] - pe2, pe2);  te2 = fmaf(0.5f, ys[i] - te2, te2);
  }
}

__device__ __forceinline__ void step1(float xx, float yy, float a, float w,
                                      float& pe, float& te, float& acc) {
  float dx = xx - pe;
  float dy = yy - te;
  pe = fmaf(a, dx, pe);
  te = fmaf(a, dy, te);
  float e   = pe - te;
  float sel = (dx * dy < 0.0f) ? w : 0.0f;  // sign(a*dx)==sign(dx); ==0 cases
  acc = fmaf(sel, e * e, acc);              // are measure-zero on random data
}

// main: all chains, masked accumulate
__device__ __forceinline__ void acc16_all(const float (&xs)[BT], const float (&ys)[BT],
    float& pe0, float& te0, float& pe1, float& te1, float& pe2, float& te2,
    float& acc) {
#pragma unroll
  for (int i = 0; i < BT; ++i) {
    step1(xs[i], ys[i], 0.1f, 0.5f, pe0, te0, acc);
    step1(xs[i], ys[i], 0.3f, 0.3f, pe1, te1, acc);
    step1(xs[i], ys[i], 0.5f, 0.2f, pe2, te2, acc);
  }
}

__global__ __launch_bounds__(256, 4) void ms_trend_loss_kernel(
    const float* __restrict__ pred, const float* __restrict__ targ,
    float* __restrict__ out) {
  const int lane = threadIdx.x & 63;
  const int wave = threadIdx.x >> 6;
  const int unit = blockIdx.x * WPB + wave;   // 0 .. BB*NCH-1 (2048)
  const int b = unit >> 6;                    // / NCH (NCH=64)
  const int c = unit & 63;                    // % NCH
  const int s = c * CH;
  const int start = (c == 0) ? 0 : (s - WU);  // >= 0 (WU < CH)

  const float* p = pred + (b * TT + start) * DD + lane;
  const float* q = targ + (b * TT + start) * DD + lane;

  float pe0, pe1, pe2, te0, te1, te2;
  float acc = 0.0f;
  // Two scalar buffer sets, alternated in straight-line code (R14 shape —
  // compiles to VGPR 48, no spill; collapse is harmless in the NT regime).
  float xa[BT], ya[BT], xb[BT], yb[BT];

  if (c == 0) {
    // exact path: 128 accumulated steps, t in [0, 128). First step re-sees
    // xa[0]: dx=dy=0 -> no-op, matching ema_0 = x_0.  Batches 0..7.
    load16(p, q, 0, xa, ya);
    load16(p, q, BT, xb, yb);
    pe0 = pe1 = pe2 = xa[0];
    te0 = te1 = te2 = ya[0];
    acc16_all(xa, ya, pe0, te0, pe1, te1, pe2, te2, acc);   // b0
    load16(p, q, 2 * BT, xa, ya);
    acc16_all(xb, yb, pe0, te0, pe1, te1, pe2, te2, acc);   // b1
    load16(p, q, 3 * BT, xb, yb);
    acc16_all(xa, ya, pe0, te0, pe1, te1, pe2, te2, acc);   // b2
    load16(p, q, 4 * BT, xa, ya);
    acc16_all(xb, yb, pe0, te0, pe1, te1, pe2, te2, acc);   // b3
    load16(p, q, 5 * BT, xb, yb);
    acc16_all(xa, ya, pe0, te0, pe1, te1, pe2, te2, acc);   // b4
    load16(p, q, 6 * BT, xa, ya);
    acc16_all(xb, yb, pe0, te0, pe1, te1, pe2, te2, acc);   // b5
    load16(p, q, 7 * BT, xb, yb);
    acc16_all(xa, ya, pe0, te0, pe1, te1, pe2, te2, acc);   // b6
    acc16_all(xb, yb, pe0, te0, pe1, te1, pe2, te2, acc);   // b7
  } else {
    // warmup t in [s-32, s-16): chain0 only; [s-16, s): all chains;
    // accumulate t in [s, s+128).  Batches 0..9 (2 warm + 8 acc).
    load16(p, q, 0, xa, ya);
    load16(p, q, BT, xb, yb);
    pe0 = xa[0];
    te0 = ya[0];
    warm16_a0(xa, ya, pe0, te0);                            // b0
    load16(p, q, 2 * BT, xa, ya);
    pe1 = pe2 = xb[0];
    te1 = te2 = yb[0];
    warm16_all(xb, yb, pe0, te0, pe1, te1, pe2, te2);       // b1
    load16(p, q, 3 * BT, xb, yb);
    acc16_all(xa, ya, pe0, te0, pe1, te1, pe2, te2, acc);   // b2
    load16(p, q, 4 * BT, xa, ya);
    acc16_all(xb, yb, pe0, te0, pe1, te1, pe2, te2, acc);   // b3
    load16(p, q, 5 * BT, xb, yb);
    acc16_all(xa, ya, pe0, te0, pe1, te1, pe2, te2, acc);   // b4
    load16(p, q, 6 * BT, xa, ya);
    acc16_all(xb, yb, pe0, te0, pe1, te1, pe2, te2, acc);   // b5
    load16(p, q, 7 * BT, xb, yb);
    acc16_all(xa, ya, pe0, te0, pe1, te1, pe2, te2, acc);   // b6
    load16(p, q, 8 * BT, xa, ya);
    acc16_all(xb, yb, pe0, te0, pe1, te1, pe2, te2, acc);   // b7
    load16(p, q, 9 * BT, xb, yb);
    acc16_all(xa, ya, pe0, te0, pe1, te1, pe2, te2, acc);   // b8
    acc16_all(xb, yb, pe0, te0, pe1, te1, pe2, te2, acc);   // b9
  }

  // wave-64 shuffle reduce -> per-block LDS reduce -> 1 atomic per block
#pragma unroll
  for (int off = 32; off > 0; off >>= 1) acc += __shfl_down(acc, off);
  __shared__ float sred[WPB];
  if (lane == 0) sred[wave] = acc;
  __syncthreads();
  if (threadIdx.x == 0) {
    float t = sred[0] + sred[1] + sred[2] + sred[3];
    atomicAdd(out, t * INV_NORM);
  }
}

extern "C" void kernel_launch(void* const* d_in, const int* in_sizes, int n_in,
                              void* d_out, int out_size, void* d_ws, size_t ws_size,
                              hipStream_t stream) {
  (void)in_sizes; (void)n_in; (void)out_size; (void)d_ws; (void)ws_size;
  const float* pred = (const float*)d_in[0];
  const float* targ = (const float*)d_in[1];
  float* out = (float*)d_out;

  zero_out_kernel<<<1, 1, 0, stream>>>(out);
  ms_trend_loss_kernel<<<BB * NCH / WPB, 256, 0, stream>>>(pred, targ, out);
}

// Round 9
// 141.995 us; speedup vs baseline: 1.5172x; 1.0086x over previous
//
#include <hip/hip_runtime.h>

// MultiScaleTrendDirectionLoss — B=32, T=8192, D=64, fp32 in, scalar fp32 out.
// R16 = R15 (nt loads, scalar two-set) + CH=256 (redundancy 1.25 -> 1.125,
// logical 167 -> 150.7 MB) + rolled 2-batch loop (constant code size).
// Evidence: R15 confirmed the NT-regime bytes model (bench -5.6µs on a
// -34 MB cut; kernel hidden below 40µs fills both rounds). Numerator is the
// only lever left; rate is ~80% of the 6.6 TB/s the harness fills prove
// sustainable. CH=256+WU=32 accuracy is HW-verified (R13b, absmax 0.0).
// Occupancy 1024 waves = 1/SIMD: post-NT sufficient (each wave keeps an 8KB
// batch in flight under ~700cy compute; 4 waves/CU covers the 10.7 B/cy/CU
// ceiling rate). Pre-NT occupancy sensitivity (R13) was the L1 cap, now
// bypassed. Falsifier: WRITE_SIZE jump (spill) or bench >= 150 -> revert R15.
// Accuracy contract: WU=32 split warmup. Chain0 warms 32 steps
// ((0.9)^32=0.034), chains 1/2 warm 16 ((0.7)^16=3e-3, (0.5)^16=2e-5).
// WU=16 for chain0 is UNSAFE (bias ~2.8e-3 vs thr 3.3e-3) — do not shrink.

namespace {
constexpr int BB  = 32;
constexpr int TT  = 8192;
constexpr int DD  = 64;
constexpr int CH  = 256;        // chunk length along T (R15: 128)
constexpr int WU  = 32;         // warmup prefix (16 a0-only + 16 all-chain)
constexpr int NCH = TT / CH;    // 32 chunks per sequence
constexpr int WPB = 4;          // waves per block (256 threads)
constexpr int BT  = 16;         // steps per load batch
// masked.mean(axis=1) /(T-1)=8191; final .mean() /(B*D)=2048
constexpr float INV_NORM = 1.0f / (8191.0f * 2048.0f);
}

__global__ void zero_out_kernel(float* o) { o[0] = 0.0f; }

__device__ __forceinline__ void load16(const float* __restrict__ p,
                                       const float* __restrict__ q, int bt,
                                       float (&xs)[BT], float (&ys)[BT]) {
#pragma unroll
  for (int i = 0; i < BT; ++i) {
    xs[i] = __builtin_nontemporal_load(p + (bt + i) * DD);
    ys[i] = __builtin_nontemporal_load(q + (bt + i) * DD);
  }
}

// warmup, chain0 only (alpha=0.1): 4 VALU/step
__device__ __forceinline__ void warm16_a0(const float (&xs)[BT], const float (&ys)[BT],
                                          float& pe0, float& te0) {
#pragma unroll
  for (int i = 0; i < BT; ++i) {
    pe0 = fmaf(0.1f, xs[i] - pe0, pe0);
    te0 = fmaf(0.1f, ys[i] - te0, te0);
  }
}

// warmup, all chains, no accumulation: 12 VALU/step
__device__ __forceinline__ void warm16_all(const float (&xs)[BT], const float (&ys)[BT],
    float& pe0, float& te0, float& pe1, float& te1, float& pe2, float& te2) {
#pragma unroll
  for (int i = 0; i < BT; ++i) {
    pe0 = fmaf(0.1f, xs[i] - pe0, pe0);  te0 = fmaf(0.1f, ys[i] - te0, te0);
    pe1 = fmaf(0.3f, xs[i] - pe1, pe1);  te1 = fmaf(0.3f, ys[i] - te1, te1);
    pe2 = fmaf(0.5f, xs[i] - pe2, pe2);  te2 = fmaf(0.5f, ys[i] - te2, te2);
  }
}

__device__ __forceinline__ void step1(float xx, float yy, float a, float w,
                                      float& pe, float& te, float& acc) {
  float dx = xx - pe;
  float dy = yy - te;
  pe = fmaf(a, dx, pe);
  te = fmaf(a, dy, te);
  float e   = pe - te;
  float sel = (dx * dy < 0.0f) ? w : 0.0f;  // sign(a*dx)==sign(dx); ==0 cases
  acc = fmaf(sel, e * e, acc);              // are measure-zero on random data
}

// main: all chains, masked accumulate
__device__ __forceinline__ void acc16_all(const float (&xs)[BT], const float (&ys)[BT],
    float& pe0, float& te0, float& pe1, float& te1, float& pe2, float& te2,
    float& acc) {
#pragma unroll
  for (int i = 0; i < BT; ++i) {
    step1(xs[i], ys[i], 0.1f, 0.5f, pe0, te0, acc);
    step1(xs[i], ys[i], 0.3f, 0.3f, pe1, te1, acc);
    step1(xs[i], ys[i], 0.5f, 0.2f, pe2, te2, acc);
  }
}

__global__ __launch_bounds__(256, 4) void ms_trend_loss_kernel(
    const float* __restrict__ pred, const float* __restrict__ targ,
    float* __restrict__ out) {
  const int lane = threadIdx.x & 63;
  const int wave = threadIdx.x >> 6;
  const int unit = blockIdx.x * WPB + wave;   // 0 .. BB*NCH-1 (1024)
  const int b = unit >> 5;                    // / NCH (NCH=32)
  const int c = unit & 31;                    // % NCH
  const int s = c * CH;
  const int start = (c == 0) ? 0 : (s - WU);  // >= 0 (WU < CH)

  const float* p = pred + (b * TT + start) * DD + lane;
  const float* q = targ + (b * TT + start) * DD + lane;

  float pe0, pe1, pe2, te0, te1, te2;
  float acc = 0.0f;
  // Two scalar buffer sets, alternated (R14/R15 shape — VGPR ~48, no spill).
  float xa[BT], ya[BT], xb[BT], yb[BT];

  // Prologue: both paths leave xa/xb holding the FIRST TWO accumulate
  // batches and set nl = index of the next batch to load into xa.
  int nl;
  load16(p, q, 0, xa, ya);
  load16(p, q, BT, xb, yb);
  if (c == 0) {
    // exact path: accumulate batches 0..15 (t in [0,256)). First step
    // re-sees xa[0]: dx=dy=0 -> no-op, matching ema_0 = x_0.
    pe0 = pe1 = pe2 = xa[0];
    te0 = te1 = te2 = ya[0];
    nl = 2;
  } else {
    // warmup t in [s-32,s-16): chain0 only (b0); [s-16,s): all chains (b1);
    // accumulate batches 2..17 (t in [s, s+256)).
    pe0 = xa[0];
    te0 = ya[0];
    warm16_a0(xa, ya, pe0, te0);                       // b0
    load16(p, q, 2 * BT, xa, ya);
    pe1 = pe2 = xb[0];                                 // == x[s-16]
    te1 = te2 = yb[0];
    warm16_all(xb, yb, pe0, te0, pe1, te1, pe2, te2);  // b1
    load16(p, q, 3 * BT, xb, yb);
    nl = 4;
  }

  // 16 accumulate batches: 7 x (2 batches + 2 reloads) + final 2 batches.
  // Register sets are statically indexed; only the load offset is runtime.
  for (int k = 0; k < 7; ++k) {
    acc16_all(xa, ya, pe0, te0, pe1, te1, pe2, te2, acc);
    load16(p, q, (nl + 2 * k) * BT, xa, ya);
    acc16_all(xb, yb, pe0, te0, pe1, te1, pe2, te2, acc);
    load16(p, q, (nl + 2 * k + 1) * BT, xb, yb);
  }
  acc16_all(xa, ya, pe0, te0, pe1, te1, pe2, te2, acc);
  acc16_all(xb, yb, pe0, te0, pe1, te1, pe2, te2, acc);

  // wave-64 shuffle reduce -> per-block LDS reduce -> 1 atomic per block
#pragma unroll
  for (int off = 32; off > 0; off >>= 1) acc += __shfl_down(acc, off);
  __shared__ float sred[WPB];
  if (lane == 0) sred[wave] = acc;
  __syncthreads();
  if (threadIdx.x == 0) {
    float t = sred[0] + sred[1] + sred[2] + sred[3];
    atomicAdd(out, t * INV_NORM);
  }
}

extern "C" void kernel_launch(void* const* d_in, const int* in_sizes, int n_in,
                              void* d_out, int out_size, void* d_ws, size_t ws_size,
                              hipStream_t stream) {
  (void)in_sizes; (void)n_in; (void)out_size; (void)d_ws; (void)ws_size;
  const float* pred = (const float*)d_in[0];
  const float* targ = (const float*)d_in[1];
  float* out = (float*)d_out;

  zero_out_kernel<<<1, 1, 0, stream>>>(out);
  ms_trend_loss_kernel<<<BB * NCH / WPB, 256, 0, stream>>>(pred, targ, out);
}